// Round 1
// baseline (138.113 us; speedup 1.0000x reference)
//
#include <hip/hip_runtime.h>

// B=8, MB=512, IN=1024, EMB=1024, H=16, KVH=4, HD=64, BS=16, K=32
//
// S[b,t,h,q]  = h[b,t] . (Wk_head @ qr[q,h,:]) / 8
// VW[b,t,h,c] = h[b,t] . (Wv_head @ (Wo@Wr)[h*64:(h+1)*64, c])
// vel[b,m,q,c] = br[c] + sum_h [win-sum E*VW] / [win-sum E],  E=exp(S)
// GEMM 4096x1024x288 via split-bf16 MFMA: C = Al*Bh + Ah*Bl + Ah*Bh.
//
// k2 redesign (this round): NO LDS staging in the main loop. Ahg/Wth are
// precomputed in MFMA fragment order (row=l16, kchunk=quad*8), so each
// fragment is a contiguous 16B v8s in global memory -> direct global loads
// (L2-served; blocks sharing an A-panel have ids differing by 64 -> same XCD).
// Each block: 64x64 tile, 4 waves, wave w owns K-quarter [w*256,(w+1)*256),
// wave-tile 64x64 (acc[4][4]), reg double-buffered fragments. One LDS
// cross-wave reduction at the end writes FINAL S/VW (no K-split partials).

typedef __attribute__((ext_vector_type(8))) short v8s;
typedef __attribute__((ext_vector_type(4))) float v4f;

// ws layout (floats) -- unchanged from previous version (S1/VW1 slots unused)
#define OFF_WOR  0u          // [1024][2]
#define OFF_QR   2048u       // [16][1024]
#define OFF_WTH  18432u      // bf16 hi, transposed [320 j][1024 i]
#define OFF_WTL  182272u     // bf16 lo
#define OFF_S0   346112u     // [2048 rows][544]  row=((b*16+q)*16+h), data at [32..544)
#define OFF_VW0  2574336u    // [256 rows][544]   row=b*32+(h*2+c)
#define OFF_AH   2852864u    // bf16 hi of h, [4096 m][1024 k]  (2097152 floats)
#define OFF_AL   4950016u    // bf16 lo
#define SROW 544

__device__ __forceinline__ void split_bf16(float a, unsigned short& h, unsigned short& l) {
    const unsigned u = __float_as_uint(a);
    h = (unsigned short)(u >> 16);
    const float r = a - __uint_as_float(u & 0xFFFF0000u);   // exact residual
    unsigned v = __float_as_uint(r);
    v += 0x7FFFu + ((v >> 16) & 1u);                        // RNE to bf16
    l = (unsigned short)(v >> 16);
}

// ---- kP: qr (proj+RoPE) | Wor = Wo@Wr | zero pads | h -> Ah/Al bf16 split ----
__global__ __launch_bounds__(256) void kP(
    const float* __restrict__ oq, const float* __restrict__ Wq,
    const float* __restrict__ fc, const float* __restrict__ fs,
    const float* __restrict__ Wo, const float* __restrict__ Wr,
    const float* __restrict__ hsrc,
    float* __restrict__ qr, float* __restrict__ Wor,
    float* __restrict__ S0, float* __restrict__ VW0,
    unsigned* __restrict__ wthu, unsigned* __restrict__ wtlu,
    unsigned short* __restrict__ Ahg, unsigned short* __restrict__ Alg)
{
    __shared__ float sm[2048];
    const int b = blockIdx.x, t = threadIdx.x;
    if (b >= 586) {
        // split h into bf16 hi/lo: 2048 elems per block, 8 per thread
        const int base = (b - 586) * 2048 + t * 8;
        const float4 x0 = *(const float4*)(hsrc + base);
        const float4 x1 = *(const float4*)(hsrc + base + 4);
        const float af[8] = {x0.x, x0.y, x0.z, x0.w, x1.x, x1.y, x1.z, x1.w};
        v8s ah, al;
        #pragma unroll
        for (int j = 0; j < 8; ++j) {
            unsigned short hh, ll;
            split_bf16(af[j], hh, ll);
            ah[j] = (short)hh; al[j] = (short)ll;
        }
        *(v8s*)(Ahg + base) = ah;
        *(v8s*)(Alg + base) = al;
        return;
    }
    if (b < 256) {
        // one (q, head) pair: 64 output cols; e-split across 4 waves
        const int q = b >> 4, h = b & 15;
        #pragma unroll
        for (int j = 0; j < 4; ++j) sm[t + 256 * j] = oq[q * 1024 + t + 256 * j];
        __syncthreads();
        const int w = t >> 6, lane = t & 63;
        const float* wq = Wq + (size_t)(w * 256) * 1024 + h * 64 + lane;
        const float* os = sm + w * 256;
        float acc = 0.f;
        #pragma unroll 16
        for (int e = 0; e < 256; ++e) acc = fmaf(os[e], wq[(size_t)e * 1024], acc);
        sm[1024 + w * 64 + lane] = acc;
        __syncthreads();
        if (t < 64) {
            const int d = t, p = d ^ 32;
            const float a1 = sm[1024 + d] + sm[1088 + d] + sm[1152 + d] + sm[1216 + d];
            const float a2 = sm[1024 + p] + sm[1088 + p] + sm[1152 + p] + sm[1216 + p];
            const float c = fc[q * 64 + d], s = fs[q * 64 + d];
            const float rh = (d < 32) ? -a2 : a2;
            qr[q * 1024 + h * 64 + d] = fmaf(a1, c, rh * s);
        }
    } else if (b < 512) {
        // Wor = Wo @ Wr  (4 rows/block, wave per row)
        #pragma unroll
        for (int j = 0; j < 8; ++j) sm[t + 256 * j] = Wr[t + 256 * j];
        __syncthreads();
        const int i = (b - 256) * 4 + (t >> 6);
        const int lane = t & 63;
        float a0 = 0.f, a1 = 0.f;
        const float* wo = Wo + (size_t)i * 1024 + lane;
        #pragma unroll
        for (int j = 0; j < 16; ++j) {
            const float w = wo[j * 64];
            const int e = lane + j * 64;
            a0 = fmaf(w, sm[2 * e], a0);
            a1 = fmaf(w, sm[2 * e + 1], a1);
        }
        #pragma unroll
        for (int w = 1; w < 64; w <<= 1) {
            a0 += __shfl_xor(a0, w, 64);
            a1 += __shfl_xor(a1, w, 64);
        }
        if (lane == 0) { Wor[i * 2] = a0; Wor[i * 2 + 1] = a1; }
    } else if (b < 584) {
        // zero left-pads (32 floats = 8 float4 per row): S0 (2048 rows) + VW0 (256 rows)
        const int idx = (b - 512) * 256 + t;  // < 18432
        const float4 z = make_float4(0.f, 0.f, 0.f, 0.f);
        if (idx < 16384)  *(float4*)(S0  + (size_t)(idx >> 3) * SROW + (idx & 7) * 4) = z;
        else              *(float4*)(VW0 + (size_t)((idx - 16384) >> 3) * SROW + (idx & 7) * 4) = z;
    } else {
        // zero Wt pad rows 288..319 (16384 u32 per array)
        unsigned* dst = (b == 584) ? wthu : wtlu;
        #pragma unroll
        for (int j = 0; j < 64; ++j) dst[147456 + t + 256 * j] = 0u;
    }
}

// ---------------- kW: folded weights -> Wth/Wtl bf16 transposed [j][i] ----------------
// per kv-group g, 16-row chunk: (16i x 64d Wk|Wv) @ (64d x 72jc)
__global__ __launch_bounds__(256) void kW(
    const float* __restrict__ Wk, const float* __restrict__ Wv,
    const float* __restrict__ qr, const float* __restrict__ Wor,
    unsigned short* __restrict__ Wth, unsigned short* __restrict__ Wtl)
{
    __shared__ float As[16 * 68];
    __shared__ float Bt[72 * 68];   // [jc][d]
    const int b = blockIdx.x, t = threadIdx.x;
    const int g = b & 3, i0 = (b >> 2) * 16;
    #pragma unroll
    for (int jj = 0; jj < 16; ++jj) {
        const int i2 = t + 256 * jj;    // < 4096
        const int d = i2 & 63, col = i2 >> 6;
        Bt[col * 68 + d] = qr[(col >> 2) * 1024 + (g * 4 + (col & 3)) * 64 + d];
    }
    #pragma unroll
    for (int jj = 0; jj < 2; ++jj) {
        const int i2 = t + 256 * jj;    // < 512
        const int d = i2 & 63, vc = i2 >> 6;
        Bt[(64 + vc) * 68 + d] = Wor[((g * 4 + (vc >> 1)) * 64 + d) * 2 + (vc & 1)];
    }
    {
        const int i = t >> 4, dc = (t & 15) * 4;
        *(float4*)&As[i * 68 + dc] = *(const float4*)(Wk + (size_t)(i0 + i) * 256 + g * 64 + dc);
    }
    __syncthreads();
    const int jc = t & 63, iq = t >> 6;
    {
        float o4[4] = {0.f, 0.f, 0.f, 0.f};
        #pragma unroll
        for (int dc = 0; dc < 16; ++dc) {
            const float4 bv = *(const float4*)&Bt[jc * 68 + dc * 4];
            #pragma unroll
            for (int r = 0; r < 4; ++r) {
                const float4 av = *(const float4*)&As[(iq * 4 + r) * 68 + dc * 4];
                o4[r] = fmaf(av.x, bv.x, o4[r]);
                o4[r] = fmaf(av.y, bv.y, o4[r]);
                o4[r] = fmaf(av.z, bv.z, o4[r]);
                o4[r] = fmaf(av.w, bv.w, o4[r]);
            }
        }
        const int j = (jc >> 2) * 16 + g * 4 + (jc & 3);
        #pragma unroll
        for (int r = 0; r < 4; ++r) {
            unsigned short hh, ll;
            split_bf16(o4[r] * 0.125f, hh, ll);   // 1/sqrt(HD) folded in
            Wth[(size_t)j * 1024 + i0 + iq * 4 + r] = hh;
            Wtl[(size_t)j * 1024 + i0 + iq * 4 + r] = ll;
        }
    }
    __syncthreads();
    {
        const int i = t >> 4, dc = (t & 15) * 4;
        *(float4*)&As[i * 68 + dc] = *(const float4*)(Wv + (size_t)(i0 + i) * 256 + g * 64 + dc);
    }
    __syncthreads();
    if (t < 128) {
        const int il = t >> 3, vc = t & 7;
        float acc = 0.f;
        #pragma unroll
        for (int dc = 0; dc < 16; ++dc) {
            const float4 av = *(const float4*)&As[il * 68 + dc * 4];
            const float4 bv = *(const float4*)&Bt[(64 + vc) * 68 + dc * 4];
            acc = fmaf(av.x, bv.x, acc);
            acc = fmaf(av.y, bv.y, acc);
            acc = fmaf(av.z, bv.z, acc);
            acc = fmaf(av.w, bv.w, acc);
        }
        const int j = 256 + (g * 4 + (vc >> 1)) * 2 + (vc & 1);
        unsigned short hh, ll;
        split_bf16(acc, hh, ll);
        Wth[(size_t)j * 1024 + i0 + il] = hh;
        Wtl[(size_t)j * 1024 + i0 + il] = ll;
    }
}

// ------- k2: no-LDS MFMA GEMM. 64x64 tile, 4 waves = 4 K-quarters, reg dbuf ------
__global__ __launch_bounds__(256, 2) void k2(
    const unsigned short* __restrict__ Ahg, const unsigned short* __restrict__ Alg,
    const unsigned short* __restrict__ Wth, const unsigned short* __restrict__ Wtl,
    float* __restrict__ S0, float* __restrict__ VW0)
{
    __shared__ float red[4][64][68];            // 68 KB, padded (+4) lane stride
    const int m0 = blockIdx.x * 64;
    const int n0 = blockIdx.y * 64;
    const int t = threadIdx.x;
    const int w = t >> 6, lane = t & 63;
    const int l16 = lane & 15, quad = lane >> 4;

    // fragment bases: row = (m0|n0) + s*16 + l16, k = w*256 + it*32 + quad*8
    const size_t aoff = (size_t)(m0 + l16) * 1024 + w * 256 + quad * 8;
    const size_t boff = (size_t)(n0 + l16) * 1024 + w * 256 + quad * 8;
    const unsigned short* pah = Ahg + aoff;
    const unsigned short* pal = Alg + aoff;
    const unsigned short* pbh = Wth + boff;
    const unsigned short* pbl = Wtl + boff;

    v4f acc[4][4];
    #pragma unroll
    for (int i = 0; i < 4; ++i)
        #pragma unroll
        for (int j = 0; j < 4; ++j) acc[i][j] = (v4f)(0.f);

    v8s fah[2][4], fal[2][4], fbh[2][4], fbl[2][4];
    #pragma unroll
    for (int s = 0; s < 4; ++s) {               // prologue: load it=0 fragments
        fah[0][s] = *(const v8s*)(pah + s * 16384);
        fal[0][s] = *(const v8s*)(pal + s * 16384);
        fbh[0][s] = *(const v8s*)(pbh + s * 16384);
        fbl[0][s] = *(const v8s*)(pbl + s * 16384);
    }
    #pragma unroll 8
    for (int it = 0; it < 8; ++it) {            // 8 x BK=32 covers this wave's 256 k
        const int cur = it & 1, nxt = cur ^ 1;
        if (it < 7) {                           // issue next-iter loads under MFMAs
            const int ko = (it + 1) * 32;
            #pragma unroll
            for (int s = 0; s < 4; ++s) {
                fah[nxt][s] = *(const v8s*)(pah + s * 16384 + ko);
                fal[nxt][s] = *(const v8s*)(pal + s * 16384 + ko);
                fbh[nxt][s] = *(const v8s*)(pbh + s * 16384 + ko);
                fbl[nxt][s] = *(const v8s*)(pbl + s * 16384 + ko);
            }
        }
        #pragma unroll
        for (int ms = 0; ms < 4; ++ms)
            #pragma unroll
            for (int ns = 0; ns < 4; ++ns) {
                acc[ms][ns] = __builtin_amdgcn_mfma_f32_16x16x32_bf16(fal[cur][ms], fbh[cur][ns], acc[ms][ns], 0, 0, 0);
                acc[ms][ns] = __builtin_amdgcn_mfma_f32_16x16x32_bf16(fah[cur][ms], fbl[cur][ns], acc[ms][ns], 0, 0, 0);
                acc[ms][ns] = __builtin_amdgcn_mfma_f32_16x16x32_bf16(fah[cur][ms], fbh[cur][ns], acc[ms][ns], 0, 0, 0);
            }
    }

    // cross-wave K reduction in LDS, then final S/VW store (no partials)
    #pragma unroll
    for (int ms = 0; ms < 4; ++ms)
        #pragma unroll
        for (int ns = 0; ns < 4; ++ns)
            *(v4f*)&red[w][lane][(ms * 4 + ns) * 4] = acc[ms][ns];
    __syncthreads();
    // thread (fg = w, lane) handles ms = fg, all ns, all r
    #pragma unroll
    for (int ns = 0; ns < 4; ++ns) {
        const int j = n0 + ns * 16 + l16;
        if (j >= 288) continue;                 // wave-uniform per ns
        const int fo = w * 16 + ns * 4;
        const v4f s0 = *(const v4f*)&red[0][lane][fo];
        const v4f s1 = *(const v4f*)&red[1][lane][fo];
        const v4f s2 = *(const v4f*)&red[2][lane][fo];
        const v4f s3 = *(const v4f*)&red[3][lane][fo];
        const v4f sv = s0 + s1 + s2 + s3;
        const int m = m0 + w * 16 + quad * 4;   // C/D: col=lane&15, row=quad*4+reg
        const int bb = m >> 9, tt = m & 511;
        float* dst = (j < 256)
            ? S0  + (size_t)((bb * 16 + (j >> 4)) * 16 + (j & 15)) * SROW + 32 + tt
            : VW0 + (size_t)(bb * 32 + (j - 256)) * SROW + 32 + tt;
        *(float4*)dst = make_float4(sv[0], sv[1], sv[2], sv[3]);
    }
}

// ---------------- k3: exp + sliding-window softmax + head-reduce (quarter-m) -------
__global__ __launch_bounds__(256) void k3(
    const float* __restrict__ S, const float* __restrict__ VW,
    const float* __restrict__ brp, float* __restrict__ out)
{
    __shared__ float Es[16 * 164];
    __shared__ float EVs[32 * 164];
    const int b = blockIdx.x, q = blockIdx.y, qt = blockIdx.z;
    const int tbase = qt * 128;
    const int t = threadIdx.x;
    for (int idx = t; idx < 640; idx += 256) {          // 16 h x 40 float4 (wi<160)
        const int h = idx / 40, g = idx - h * 40;
        const size_t off = (size_t)((b * 16 + q) * 16 + h) * SROW + tbase + g * 4;
        const float4 a = *(const float4*)(S + off);
        float4 e;
        e.x = __expf(a.x); e.y = __expf(a.y);
        e.z = __expf(a.z); e.w = __expf(a.w);
        *(float4*)(Es + h * 164 + g * 4) = e;
    }
    __syncthreads();
    for (int idx = t; idx < 1280; idx += 256) {         // 32 hc x 40 float4
        const int hc = idx / 40, g = idx - hc * 40;
        const size_t off = (size_t)(b * 32 + hc) * SROW + tbase + g * 4;
        const float4 v0 = *(const float4*)(VW + off);
        const float4 e = *(const float4*)(Es + (hc >> 1) * 164 + g * 4);
        float4 rr;
        rr.x = e.x * v0.x; rr.y = e.y * v0.y;
        rr.z = e.z * v0.z; rr.w = e.w * v0.w;
        *(float4*)(EVs + hc * 164 + g * 4) = rr;
    }
    __syncthreads();
    const int h = t & 15, mg = t >> 4;
    const float* ep = Es + h * 164 + mg * 8;
    const float* e0 = EVs + (2 * h) * 164 + mg * 8;
    const float* e1 = EVs + (2 * h + 1) * 164 + mg * 8;
    float den = 0.f, n0s = 0.f, n1s = 0.f;
    #pragma unroll
    for (int s = 0; s < 32; ++s) {
        const int ss = 1 + ((s + 2 * h) & 31);          // bank-rotated
        den += ep[ss]; n0s += e0[ss]; n1s += e1[ss];
    }
    const float br0 = brp[0], br1 = brp[1];
    #pragma unroll
    for (int u = 0; u < 8; ++u) {
        const float inv = __builtin_amdgcn_rcpf(den);
        float c0 = n0s * inv, c1 = n1s * inv;
        #pragma unroll
        for (int w = 1; w < 16; w <<= 1) {
            c0 += __shfl_xor(c0, w, 64);
            c1 += __shfl_xor(c1, w, 64);
        }
        if (h == 0) {
            const int m = tbase + mg * 8 + u;
            float* o = out + (size_t)((b * 512 + m) * 16 + q) * 2;
            o[0] = c0 + br0;
            o[1] = c1 + br1;
        }
        if (u < 7) {
            den += ep[33 + u] - ep[1 + u];
            n0s += e0[33 + u] - e0[1 + u];
            n1s += e1[33 + u] - e1[1 + u];
        }
    }
}

extern "C" void kernel_launch(void* const* d_in, const int* in_sizes, int n_in,
                              void* d_out, int out_size, void* d_ws, size_t ws_size,
                              hipStream_t stream)
{
    (void)in_sizes; (void)n_in; (void)out_size; (void)ws_size;
    const float* h  = (const float*)d_in[0];
    const float* fc = (const float*)d_in[1];
    const float* fs = (const float*)d_in[2];
    const float* Wq = (const float*)d_in[3];
    const float* Wk = (const float*)d_in[4];
    const float* Wv = (const float*)d_in[5];
    const float* Wo = (const float*)d_in[6];
    const float* oq = (const float*)d_in[7];
    const float* Wr = (const float*)d_in[8];
    const float* br = (const float*)d_in[9];
    float* ws = (float*)d_ws;
    float* Wor  = ws + OFF_WOR;
    float* qr   = ws + OFF_QR;
    unsigned short* Wth = (unsigned short*)(ws + OFF_WTH);
    unsigned short* Wtl = (unsigned short*)(ws + OFF_WTL);
    float* S0   = ws + OFF_S0;
    float* VW0  = ws + OFF_VW0;
    unsigned short* Ahg = (unsigned short*)(ws + OFF_AH);
    unsigned short* Alg = (unsigned short*)(ws + OFF_AL);
    float* out = (float*)d_out;

    hipLaunchKernelGGL(kP, dim3(2634), dim3(256), 0, stream,
                       oq, Wq, fc, fs, Wo, Wr, h, qr, Wor, S0, VW0,
                       (unsigned*)Wth, (unsigned*)Wtl, Ahg, Alg);
    hipLaunchKernelGGL(kW, dim3(256), dim3(256), 0, stream, Wk, Wv, qr, Wor, Wth, Wtl);
    hipLaunchKernelGGL(k2, dim3(64, 5), dim3(256), 0, stream, Ahg, Alg, Wth, Wtl, S0, VW0);
    hipLaunchKernelGGL(k3, dim3(8, 16, 4), dim3(256), 0, stream, S0, VW0, br, out);
}

// Round 2
// 122.440 us; speedup vs baseline: 1.1280x; 1.1280x over previous
//
#include <hip/hip_runtime.h>

// B=8, MB=512, IN=1024, EMB=1024, H=16, KVH=4, HD=64, BS=16, K=32
//
// S[b,t,h,q]  = h[b,t] . (Wk_head @ qr[q,h,:]) / 8
// VW[b,t,h,c] = h[b,t] . (Wv_head @ (Wo@Wr)[h*64:(h+1)*64, c])
// vel[b,m,q,c] = br[c] + sum_h [win-sum E*VW] / [win-sum E],  E=exp(S)
// GEMM 4096x1024x288 via split-bf16 MFMA: C = Al*Bh + Ah*Bl + Ah*Bh.
//
// This round: FRAGMENT-PACKED operand layout. A and B are stored as
// [rb16][kb32][quad][l16][8k] so a wave's MFMA fragment load is ONE
// contiguous 1KB global_load_dwordx4 (was 16 scattered 64B segments at
// 2KB row stride). kP repacks h through LDS (both global sides coalesced);
// kW writes packed indices directly. k2: tile 64x48 (288=6x48, no pad
// cols -> -10% MFMA), grid (64,6)=384 blocks (balanced 1.5/CU), 4 waves
// x K-quarter, reg dbuf, 52KB LDS cross-wave reduce, final S/VW output.

typedef __attribute__((ext_vector_type(8))) short v8s;
typedef __attribute__((ext_vector_type(4))) float v4f;

// ws layout (floats)
#define OFF_WOR  0u          // [1024][2]
#define OFF_QR   2048u       // [16][1024]
#define OFF_WTH  18432u      // bf16 hi, packed [18 jb][32 kb][4 quad][16 l][8]
#define OFF_WTL  182272u     // bf16 lo
#define OFF_S0   346112u     // [2048 rows][544]  row=((b*16+q)*16+h), data at [32..544)
#define OFF_VW0  2574336u    // [256 rows][544]   row=b*32+(h*2+c)
#define OFF_AH   2852864u    // bf16 hi of h, packed [256 mb][32 kb][4 quad][16 l][8]
#define OFF_AL   4950016u    // bf16 lo
#define SROW 544

__device__ __forceinline__ void split_bf16(float a, unsigned short& h, unsigned short& l) {
    const unsigned u = __float_as_uint(a);
    h = (unsigned short)(u >> 16);
    const float r = a - __uint_as_float(u & 0xFFFF0000u);   // exact residual
    unsigned v = __float_as_uint(r);
    v += 0x7FFFu + ((v >> 16) & 1u);                        // RNE to bf16
    l = (unsigned short)(v >> 16);
}

// packed index for element (row j, k i):  jb=j>>4, kb=i>>5, quad=(i>>3)&3, l=j&15, kk=i&7
__device__ __forceinline__ size_t pidx(int j, int i) {
    return (size_t)(j >> 4) * 16384 + (size_t)((i >> 5)) * 512
         + (size_t)(((i >> 3) & 3) * 128 + (j & 15) * 8 + (i & 7));
}

// ---- kP: h -> packed Ah/Al (LDS transpose) | qr (proj+RoPE) | Wor | zero pads ----
__global__ __launch_bounds__(256) void kP(
    const float* __restrict__ oq, const float* __restrict__ Wq,
    const float* __restrict__ fc, const float* __restrict__ fs,
    const float* __restrict__ Wo, const float* __restrict__ Wr,
    const float* __restrict__ hsrc,
    float* __restrict__ qr, float* __restrict__ Wor,
    float* __restrict__ S0, float* __restrict__ VW0,
    unsigned short* __restrict__ Ahg, unsigned short* __restrict__ Alg)
{
    __shared__ unsigned short Hs[2][16][520];    // 33.3 KB; row stride 1040B (16B mult)
    float* sm = (float*)&Hs[0][0][0];            // alias for qr/Wor sections (8KB used)
    const int b = blockIdx.x, t = threadIdx.x;
    if (b < 512) {
        // h-split + repack: block = 16 rows x 512 k  (mb = b>>1, kseg = b&1)
        const int mb = b >> 1, kseg = b & 1;
        const int w = t >> 6, lane = t & 63;
        #pragma unroll
        for (int i = 0; i < 4; ++i) {
            const int r = i * 4 + w;
            const float* src = hsrc + (size_t)(mb * 16 + r) * 1024 + kseg * 512 + lane * 8;
            const float4 x0 = *(const float4*)src;
            const float4 x1 = *(const float4*)(src + 4);
            const float af[8] = {x0.x, x0.y, x0.z, x0.w, x1.x, x1.y, x1.z, x1.w};
            v8s hh, ll;
            #pragma unroll
            for (int j = 0; j < 8; ++j) {
                unsigned short ah, al;
                split_bf16(af[j], ah, al);
                hh[j] = (short)ah; ll[j] = (short)al;
            }
            *(v8s*)&Hs[0][r][lane * 8] = hh;
            *(v8s*)&Hs[1][r][lane * 8] = ll;
        }
        __syncthreads();
        // write packed: region = mb*16384 + kseg*8192, slot o = i*2048 + t*8
        unsigned short* dh = Ahg + (size_t)mb * 16384 + kseg * 8192;
        unsigned short* dl = Alg + (size_t)mb * 16384 + kseg * 8192;
        const int l16 = lane & 15, quad = lane >> 4;
        #pragma unroll
        for (int i = 0; i < 4; ++i) {
            const int kc = (i * 4 + w) * 32 + quad * 8;   // local col in [0,512)
            const v8s hh = *(const v8s*)&Hs[0][l16][kc];
            const v8s ll = *(const v8s*)&Hs[1][l16][kc];
            *(v8s*)(dh + i * 2048 + t * 8) = hh;
            *(v8s*)(dl + i * 2048 + t * 8) = ll;
        }
        return;
    }
    if (b < 768) {
        // one (q, head) pair: 64 output cols; e-split across 4 waves
        const int b2 = b - 512;
        const int q = b2 >> 4, h = b2 & 15;
        #pragma unroll
        for (int j = 0; j < 4; ++j) sm[t + 256 * j] = oq[q * 1024 + t + 256 * j];
        __syncthreads();
        const int w = t >> 6, lane = t & 63;
        const float* wq = Wq + (size_t)(w * 256) * 1024 + h * 64 + lane;
        const float* os = sm + w * 256;
        float acc = 0.f;
        #pragma unroll 16
        for (int e = 0; e < 256; ++e) acc = fmaf(os[e], wq[(size_t)e * 1024], acc);
        sm[1024 + w * 64 + lane] = acc;
        __syncthreads();
        if (t < 64) {
            const int d = t, p = d ^ 32;
            const float a1 = sm[1024 + d] + sm[1088 + d] + sm[1152 + d] + sm[1216 + d];
            const float a2 = sm[1024 + p] + sm[1088 + p] + sm[1152 + p] + sm[1216 + p];
            const float c = fc[q * 64 + d], s = fs[q * 64 + d];
            const float rh = (d < 32) ? -a2 : a2;
            qr[q * 1024 + h * 64 + d] = fmaf(a1, c, rh * s);
        }
    } else if (b < 1024) {
        // Wor = Wo @ Wr  (4 rows/block, wave per row)
        #pragma unroll
        for (int j = 0; j < 8; ++j) sm[t + 256 * j] = Wr[t + 256 * j];
        __syncthreads();
        const int i = (b - 768) * 4 + (t >> 6);
        const int lane = t & 63;
        float a0 = 0.f, a1 = 0.f;
        const float* wo = Wo + (size_t)i * 1024 + lane;
        #pragma unroll
        for (int j = 0; j < 16; ++j) {
            const float w = wo[j * 64];
            const int e = lane + j * 64;
            a0 = fmaf(w, sm[2 * e], a0);
            a1 = fmaf(w, sm[2 * e + 1], a1);
        }
        #pragma unroll
        for (int w = 1; w < 64; w <<= 1) {
            a0 += __shfl_xor(a0, w, 64);
            a1 += __shfl_xor(a1, w, 64);
        }
        if (lane == 0) { Wor[i * 2] = a0; Wor[i * 2 + 1] = a1; }
    } else {
        // zero left-pads (32 floats = 8 float4 per row): S0 (2048 rows) + VW0 (256 rows)
        const int idx = (b - 1024) * 256 + t;  // < 18432
        const float4 z = make_float4(0.f, 0.f, 0.f, 0.f);
        if (idx < 16384)  *(float4*)(S0  + (size_t)(idx >> 3) * SROW + (idx & 7) * 4) = z;
        else              *(float4*)(VW0 + (size_t)((idx - 16384) >> 3) * SROW + (idx & 7) * 4) = z;
    }
}

// ---------------- kW: folded weights -> packed Wth/Wtl bf16 [j][i]-packed ----------------
// per kv-group g, 16-row chunk: (16i x 64d Wk|Wv) @ (64d x 72jc)
__global__ __launch_bounds__(256) void kW(
    const float* __restrict__ Wk, const float* __restrict__ Wv,
    const float* __restrict__ qr, const float* __restrict__ Wor,
    unsigned short* __restrict__ Wth, unsigned short* __restrict__ Wtl)
{
    __shared__ float As[16 * 68];
    __shared__ float Bt[72 * 68];   // [jc][d]
    const int b = blockIdx.x, t = threadIdx.x;
    const int g = b & 3, i0 = (b >> 2) * 16;
    #pragma unroll
    for (int jj = 0; jj < 16; ++jj) {
        const int i2 = t + 256 * jj;    // < 4096
        const int d = i2 & 63, col = i2 >> 6;
        Bt[col * 68 + d] = qr[(col >> 2) * 1024 + (g * 4 + (col & 3)) * 64 + d];
    }
    #pragma unroll
    for (int jj = 0; jj < 2; ++jj) {
        const int i2 = t + 256 * jj;    // < 512
        const int d = i2 & 63, vc = i2 >> 6;
        Bt[(64 + vc) * 68 + d] = Wor[((g * 4 + (vc >> 1)) * 64 + d) * 2 + (vc & 1)];
    }
    {
        const int i = t >> 4, dc = (t & 15) * 4;
        *(float4*)&As[i * 68 + dc] = *(const float4*)(Wk + (size_t)(i0 + i) * 256 + g * 64 + dc);
    }
    __syncthreads();
    const int jc = t & 63, iq = t >> 6;
    {
        float o4[4] = {0.f, 0.f, 0.f, 0.f};
        #pragma unroll
        for (int dc = 0; dc < 16; ++dc) {
            const float4 bv = *(const float4*)&Bt[jc * 68 + dc * 4];
            #pragma unroll
            for (int r = 0; r < 4; ++r) {
                const float4 av = *(const float4*)&As[(iq * 4 + r) * 68 + dc * 4];
                o4[r] = fmaf(av.x, bv.x, o4[r]);
                o4[r] = fmaf(av.y, bv.y, o4[r]);
                o4[r] = fmaf(av.z, bv.z, o4[r]);
                o4[r] = fmaf(av.w, bv.w, o4[r]);
            }
        }
        const int j = (jc >> 2) * 16 + g * 4 + (jc & 3);
        #pragma unroll
        for (int r = 0; r < 4; ++r) {
            unsigned short hh, ll;
            split_bf16(o4[r] * 0.125f, hh, ll);   // 1/sqrt(HD) folded in
            const size_t o = pidx(j, i0 + iq * 4 + r);
            Wth[o] = hh;
            Wtl[o] = ll;
        }
    }
    __syncthreads();
    {
        const int i = t >> 4, dc = (t & 15) * 4;
        *(float4*)&As[i * 68 + dc] = *(const float4*)(Wv + (size_t)(i0 + i) * 256 + g * 64 + dc);
    }
    __syncthreads();
    if (t < 128) {
        const int il = t >> 3, vc = t & 7;
        float acc = 0.f;
        #pragma unroll
        for (int dc = 0; dc < 16; ++dc) {
            const float4 av = *(const float4*)&As[il * 68 + dc * 4];
            const float4 bv = *(const float4*)&Bt[(64 + vc) * 68 + dc * 4];
            acc = fmaf(av.x, bv.x, acc);
            acc = fmaf(av.y, bv.y, acc);
            acc = fmaf(av.z, bv.z, acc);
            acc = fmaf(av.w, bv.w, acc);
        }
        const int j = 256 + (g * 4 + (vc >> 1)) * 2 + (vc & 1);
        unsigned short hh, ll;
        split_bf16(acc, hh, ll);
        const size_t o = pidx(j, i0 + il);
        Wth[o] = hh;
        Wtl[o] = ll;
    }
}

// ------- k2: MFMA GEMM, tile 64x48, 4 waves = 4 K-quarters, contiguous 1KB loads ------
__global__ __launch_bounds__(256, 2) void k2(
    const unsigned short* __restrict__ Ahg, const unsigned short* __restrict__ Alg,
    const unsigned short* __restrict__ Wth, const unsigned short* __restrict__ Wtl,
    float* __restrict__ S0, float* __restrict__ VW0)
{
    __shared__ float red[4][64][52];            // 52 KB, stride 52 dw (bank-floor)
    const int m0 = blockIdx.x * 64;
    const int by = blockIdx.y;                  // n0 = by*48
    const int t = threadIdx.x;
    const int w = t >> 6, lane = t & 63;
    const int l16 = lane & 15, quad = lane >> 4;

    // packed bases: region (rb, kb) at rb*16384 + kb*512; wave w owns kb = w*8 + it
    const size_t abase = (size_t)blockIdx.x * 4 * 16384 + (size_t)w * 8 * 512 + lane * 8;
    const size_t bbase = (size_t)by * 3 * 16384 + (size_t)w * 8 * 512 + lane * 8;
    const unsigned short* pah = Ahg + abase;
    const unsigned short* pal = Alg + abase;
    const unsigned short* pbh = Wth + bbase;
    const unsigned short* pbl = Wtl + bbase;

    v4f acc[4][3];
    #pragma unroll
    for (int i = 0; i < 4; ++i)
        #pragma unroll
        for (int j = 0; j < 3; ++j) acc[i][j] = (v4f)(0.f);

    v8s fah[2][4], fal[2][4], fbh[2][3], fbl[2][3];
    #pragma unroll
    for (int s = 0; s < 4; ++s) {               // prologue: it=0 fragments (1KB each)
        fah[0][s] = *(const v8s*)(pah + s * 16384);
        fal[0][s] = *(const v8s*)(pal + s * 16384);
    }
    #pragma unroll
    for (int s = 0; s < 3; ++s) {
        fbh[0][s] = *(const v8s*)(pbh + s * 16384);
        fbl[0][s] = *(const v8s*)(pbl + s * 16384);
    }
    #pragma unroll 8
    for (int it = 0; it < 8; ++it) {            // 8 x BK=32 covers this wave's 256 k
        const int cur = it & 1, nxt = cur ^ 1;
        if (it < 7) {                           // issue next-iter loads under MFMAs
            const int ko = (it + 1) * 512;
            #pragma unroll
            for (int s = 0; s < 4; ++s) {
                fah[nxt][s] = *(const v8s*)(pah + s * 16384 + ko);
                fal[nxt][s] = *(const v8s*)(pal + s * 16384 + ko);
            }
            #pragma unroll
            for (int s = 0; s < 3; ++s) {
                fbh[nxt][s] = *(const v8s*)(pbh + s * 16384 + ko);
                fbl[nxt][s] = *(const v8s*)(pbl + s * 16384 + ko);
            }
        }
        #pragma unroll
        for (int ms = 0; ms < 4; ++ms)
            #pragma unroll
            for (int ns = 0; ns < 3; ++ns) {
                acc[ms][ns] = __builtin_amdgcn_mfma_f32_16x16x32_bf16(fal[cur][ms], fbh[cur][ns], acc[ms][ns], 0, 0, 0);
                acc[ms][ns] = __builtin_amdgcn_mfma_f32_16x16x32_bf16(fah[cur][ms], fbl[cur][ns], acc[ms][ns], 0, 0, 0);
                acc[ms][ns] = __builtin_amdgcn_mfma_f32_16x16x32_bf16(fah[cur][ms], fbh[cur][ns], acc[ms][ns], 0, 0, 0);
            }
    }

    // cross-wave K reduction in LDS, then final S/VW store (no partials)
    #pragma unroll
    for (int ms = 0; ms < 4; ++ms)
        #pragma unroll
        for (int ns = 0; ns < 3; ++ns)
            *(v4f*)&red[w][lane][(ms * 3 + ns) * 4] = acc[ms][ns];
    __syncthreads();
    // thread (w, lane) outputs the ms = w row-block, all ns
    #pragma unroll
    for (int ns = 0; ns < 3; ++ns) {
        const int j = by * 48 + ns * 16 + l16;  // < 288 always
        const int fo = (w * 3 + ns) * 4;
        const v4f s0 = *(const v4f*)&red[0][lane][fo];
        const v4f s1 = *(const v4f*)&red[1][lane][fo];
        const v4f s2 = *(const v4f*)&red[2][lane][fo];
        const v4f s3 = *(const v4f*)&red[3][lane][fo];
        const v4f sv = s0 + s1 + s2 + s3;
        const int m = m0 + w * 16 + quad * 4;   // C/D: col=lane&15, row=quad*4+reg
        const int bb = m >> 9, tt = m & 511;
        float* dst = (j < 256)                  // wave-uniform per (by, ns)
            ? S0  + (size_t)((bb * 16 + (j >> 4)) * 16 + (j & 15)) * SROW + 32 + tt
            : VW0 + (size_t)(bb * 32 + (j - 256)) * SROW + 32 + tt;
        *(float4*)dst = make_float4(sv[0], sv[1], sv[2], sv[3]);
    }
}

// ---------------- k3: exp + sliding-window softmax + head-reduce (quarter-m) -------
__global__ __launch_bounds__(256) void k3(
    const float* __restrict__ S, const float* __restrict__ VW,
    const float* __restrict__ brp, float* __restrict__ out)
{
    __shared__ float Es[16 * 164];
    __shared__ float EVs[32 * 164];
    const int b = blockIdx.x, q = blockIdx.y, qt = blockIdx.z;
    const int tbase = qt * 128;
    const int t = threadIdx.x;
    for (int idx = t; idx < 640; idx += 256) {          // 16 h x 40 float4 (wi<160)
        const int h = idx / 40, g = idx - h * 40;
        const size_t off = (size_t)((b * 16 + q) * 16 + h) * SROW + tbase + g * 4;
        const float4 a = *(const float4*)(S + off);
        float4 e;
        e.x = __expf(a.x); e.y = __expf(a.y);
        e.z = __expf(a.z); e.w = __expf(a.w);
        *(float4*)(Es + h * 164 + g * 4) = e;
    }
    __syncthreads();
    for (int idx = t; idx < 1280; idx += 256) {         // 32 hc x 40 float4
        const int hc = idx / 40, g = idx - hc * 40;
        const size_t off = (size_t)(b * 32 + hc) * SROW + tbase + g * 4;
        const float4 v0 = *(const float4*)(VW + off);
        const float4 e = *(const float4*)(Es + (hc >> 1) * 164 + g * 4);
        float4 rr;
        rr.x = e.x * v0.x; rr.y = e.y * v0.y;
        rr.z = e.z * v0.z; rr.w = e.w * v0.w;
        *(float4*)(EVs + hc * 164 + g * 4) = rr;
    }
    __syncthreads();
    const int h = t & 15, mg = t >> 4;
    const float* ep = Es + h * 164 + mg * 8;
    const float* e0 = EVs + (2 * h) * 164 + mg * 8;
    const float* e1 = EVs + (2 * h + 1) * 164 + mg * 8;
    float den = 0.f, n0s = 0.f, n1s = 0.f;
    #pragma unroll
    for (int s = 0; s < 32; ++s) {
        const int ss = 1 + ((s + 2 * h) & 31);          // bank-rotated
        den += ep[ss]; n0s += e0[ss]; n1s += e1[ss];
    }
    const float br0 = brp[0], br1 = brp[1];
    #pragma unroll
    for (int u = 0; u < 8; ++u) {
        const float inv = __builtin_amdgcn_rcpf(den);
        float c0 = n0s * inv, c1 = n1s * inv;
        #pragma unroll
        for (int w = 1; w < 16; w <<= 1) {
            c0 += __shfl_xor(c0, w, 64);
            c1 += __shfl_xor(c1, w, 64);
        }
        if (h == 0) {
            const int m = tbase + mg * 8 + u;
            float* o = out + (size_t)((b * 512 + m) * 16 + q) * 2;
            o[0] = c0 + br0;
            o[1] = c1 + br1;
        }
        if (u < 7) {
            den += ep[33 + u] - ep[1 + u];
            n0s += e0[33 + u] - e0[1 + u];
            n1s += e1[33 + u] - e1[1 + u];
        }
    }
}

extern "C" void kernel_launch(void* const* d_in, const int* in_sizes, int n_in,
                              void* d_out, int out_size, void* d_ws, size_t ws_size,
                              hipStream_t stream)
{
    (void)in_sizes; (void)n_in; (void)out_size; (void)ws_size;
    const float* h  = (const float*)d_in[0];
    const float* fc = (const float*)d_in[1];
    const float* fs = (const float*)d_in[2];
    const float* Wq = (const float*)d_in[3];
    const float* Wk = (const float*)d_in[4];
    const float* Wv = (const float*)d_in[5];
    const float* Wo = (const float*)d_in[6];
    const float* oq = (const float*)d_in[7];
    const float* Wr = (const float*)d_in[8];
    const float* br = (const float*)d_in[9];
    float* ws = (float*)d_ws;
    float* Wor  = ws + OFF_WOR;
    float* qr   = ws + OFF_QR;
    unsigned short* Wth = (unsigned short*)(ws + OFF_WTH);
    unsigned short* Wtl = (unsigned short*)(ws + OFF_WTL);
    float* S0   = ws + OFF_S0;
    float* VW0  = ws + OFF_VW0;
    unsigned short* Ahg = (unsigned short*)(ws + OFF_AH);
    unsigned short* Alg = (unsigned short*)(ws + OFF_AL);
    float* out = (float*)d_out;

    hipLaunchKernelGGL(kP, dim3(1096), dim3(256), 0, stream,
                       oq, Wq, fc, fs, Wo, Wr, h, qr, Wor, S0, VW0, Ahg, Alg);
    hipLaunchKernelGGL(kW, dim3(256), dim3(256), 0, stream, Wk, Wv, qr, Wor, Wth, Wtl);
    hipLaunchKernelGGL(k2, dim3(64, 6), dim3(256), 0, stream, Ahg, Alg, Wth, Wtl, S0, VW0);
    hipLaunchKernelGGL(k3, dim3(8, 16, 4), dim3(256), 0, stream, S0, VW0, br, out);
}

// Round 3
// 116.589 us; speedup vs baseline: 1.1846x; 1.0502x over previous
//
#include <hip/hip_runtime.h>

// B=8, MB=512, IN=1024, EMB=1024, H=16, KVH=4, HD=64, BS=16, K=32
//
// S[b,t,h,q]  = h[b,t] . (Wk_head @ qr[q,h,:]) / 8
// VW[b,t,h,c] = h[b,t] . (Wv_head @ (Wo@Wr)[h*64:(h+1)*64, c])
// vel[b,m,q,c] = br[c] + sum_h [win-sum E*VW] / [win-sum E],  E=exp(S)
// GEMM 4096x1024x288 via split-bf16 MFMA: C = Al*Bh + Ah*Bl + Ah*Bh.
//
// Fragment-packed operand layout: A and B stored as [rb16][kb32][quad][l16][8k]
// so a wave's MFMA fragment load is ONE contiguous 1KB global_load_dwordx4.
// This round: (1) s_setprio(1) around k2's MFMA cluster (4 barrier-free waves
// = role-diverse regime where setprio pays); (2) kP dispatch order: latency-
// chained qr/Wor first, cheap zero-pad blocks last (they eat the 2nd
// occupancy round at 1096 blocks > ~1024 resident).

typedef __attribute__((ext_vector_type(8))) short v8s;
typedef __attribute__((ext_vector_type(4))) float v4f;

// ws layout (floats)
#define OFF_WOR  0u          // [1024][2]
#define OFF_QR   2048u       // [16][1024]
#define OFF_WTH  18432u      // bf16 hi, packed [18 jb][32 kb][4 quad][16 l][8]
#define OFF_WTL  182272u     // bf16 lo
#define OFF_S0   346112u     // [2048 rows][544]  row=((b*16+q)*16+h), data at [32..544)
#define OFF_VW0  2574336u    // [256 rows][544]   row=b*32+(h*2+c)
#define OFF_AH   2852864u    // bf16 hi of h, packed [256 mb][32 kb][4 quad][16 l][8]
#define OFF_AL   4950016u    // bf16 lo
#define SROW 544

__device__ __forceinline__ void split_bf16(float a, unsigned short& h, unsigned short& l) {
    const unsigned u = __float_as_uint(a);
    h = (unsigned short)(u >> 16);
    const float r = a - __uint_as_float(u & 0xFFFF0000u);   // exact residual
    unsigned v = __float_as_uint(r);
    v += 0x7FFFu + ((v >> 16) & 1u);                        // RNE to bf16
    l = (unsigned short)(v >> 16);
}

// packed index for element (row j, k i):  jb=j>>4, kb=i>>5, quad=(i>>3)&3, l=j&15, kk=i&7
__device__ __forceinline__ size_t pidx(int j, int i) {
    return (size_t)(j >> 4) * 16384 + (size_t)((i >> 5)) * 512
         + (size_t)(((i >> 3) & 3) * 128 + (j & 15) * 8 + (i & 7));
}

// ---- kP: qr (proj+RoPE) | Wor = Wo@Wr | h -> packed Ah/Al | zero pads (last) ----
__global__ __launch_bounds__(256) void kP(
    const float* __restrict__ oq, const float* __restrict__ Wq,
    const float* __restrict__ fc, const float* __restrict__ fs,
    const float* __restrict__ Wo, const float* __restrict__ Wr,
    const float* __restrict__ hsrc,
    float* __restrict__ qr, float* __restrict__ Wor,
    float* __restrict__ S0, float* __restrict__ VW0,
    unsigned short* __restrict__ Ahg, unsigned short* __restrict__ Alg)
{
    __shared__ unsigned short Hs[2][16][520];    // 33.3 KB; row stride 1040B (16B mult)
    float* sm = (float*)&Hs[0][0][0];            // alias for qr/Wor sections (8KB used)
    const int b = blockIdx.x, t = threadIdx.x;
    if (b < 256) {
        // one (q, head) pair: 64 output cols; e-split across 4 waves
        const int q = b >> 4, h = b & 15;
        #pragma unroll
        for (int j = 0; j < 4; ++j) sm[t + 256 * j] = oq[q * 1024 + t + 256 * j];
        __syncthreads();
        const int w = t >> 6, lane = t & 63;
        const float* wq = Wq + (size_t)(w * 256) * 1024 + h * 64 + lane;
        const float* os = sm + w * 256;
        float acc = 0.f;
        #pragma unroll 16
        for (int e = 0; e < 256; ++e) acc = fmaf(os[e], wq[(size_t)e * 1024], acc);
        sm[1024 + w * 64 + lane] = acc;
        __syncthreads();
        if (t < 64) {
            const int d = t, p = d ^ 32;
            const float a1 = sm[1024 + d] + sm[1088 + d] + sm[1152 + d] + sm[1216 + d];
            const float a2 = sm[1024 + p] + sm[1088 + p] + sm[1152 + p] + sm[1216 + p];
            const float c = fc[q * 64 + d], s = fs[q * 64 + d];
            const float rh = (d < 32) ? -a2 : a2;
            qr[q * 1024 + h * 64 + d] = fmaf(a1, c, rh * s);
        }
        return;
    }
    if (b < 512) {
        // Wor = Wo @ Wr  (4 rows/block, wave per row)
        #pragma unroll
        for (int j = 0; j < 8; ++j) sm[t + 256 * j] = Wr[t + 256 * j];
        __syncthreads();
        const int i = (b - 256) * 4 + (t >> 6);
        const int lane = t & 63;
        float a0 = 0.f, a1 = 0.f;
        const float* wo = Wo + (size_t)i * 1024 + lane;
        #pragma unroll
        for (int j = 0; j < 16; ++j) {
            const float w = wo[j * 64];
            const int e = lane + j * 64;
            a0 = fmaf(w, sm[2 * e], a0);
            a1 = fmaf(w, sm[2 * e + 1], a1);
        }
        #pragma unroll
        for (int w = 1; w < 64; w <<= 1) {
            a0 += __shfl_xor(a0, w, 64);
            a1 += __shfl_xor(a1, w, 64);
        }
        if (lane == 0) { Wor[i * 2] = a0; Wor[i * 2 + 1] = a1; }
        return;
    }
    if (b < 1024) {
        // h-split + repack: block = 16 rows x 512 k  (mb, kseg)
        const int b2 = b - 512;
        const int mb = b2 >> 1, kseg = b2 & 1;
        const int w = t >> 6, lane = t & 63;
        #pragma unroll
        for (int i = 0; i < 4; ++i) {
            const int r = i * 4 + w;
            const float* src = hsrc + (size_t)(mb * 16 + r) * 1024 + kseg * 512 + lane * 8;
            const float4 x0 = *(const float4*)src;
            const float4 x1 = *(const float4*)(src + 4);
            const float af[8] = {x0.x, x0.y, x0.z, x0.w, x1.x, x1.y, x1.z, x1.w};
            v8s hh, ll;
            #pragma unroll
            for (int j = 0; j < 8; ++j) {
                unsigned short ah, al;
                split_bf16(af[j], ah, al);
                hh[j] = (short)ah; ll[j] = (short)al;
            }
            *(v8s*)&Hs[0][r][lane * 8] = hh;
            *(v8s*)&Hs[1][r][lane * 8] = ll;
        }
        __syncthreads();
        // write packed: region = mb*16384 + kseg*8192, slot o = i*2048 + t*8
        unsigned short* dh = Ahg + (size_t)mb * 16384 + kseg * 8192;
        unsigned short* dl = Alg + (size_t)mb * 16384 + kseg * 8192;
        const int l16 = lane & 15, quad = lane >> 4;
        #pragma unroll
        for (int i = 0; i < 4; ++i) {
            const int kc = (i * 4 + w) * 32 + quad * 8;   // local col in [0,512)
            const v8s hh = *(const v8s*)&Hs[0][l16][kc];
            const v8s ll = *(const v8s*)&Hs[1][l16][kc];
            *(v8s*)(dh + i * 2048 + t * 8) = hh;
            *(v8s*)(dl + i * 2048 + t * 8) = ll;
        }
        return;
    }
    // zero left-pads (32 floats = 8 float4 per row): S0 (2048 rows) + VW0 (256 rows)
    const int idx = (b - 1024) * 256 + t;  // < 18432
    const float4 z = make_float4(0.f, 0.f, 0.f, 0.f);
    if (idx < 16384)  *(float4*)(S0  + (size_t)(idx >> 3) * SROW + (idx & 7) * 4) = z;
    else              *(float4*)(VW0 + (size_t)((idx - 16384) >> 3) * SROW + (idx & 7) * 4) = z;
}

// ---------------- kW: folded weights -> packed Wth/Wtl bf16 [j][i]-packed ----------------
// per kv-group g, 16-row chunk: (16i x 64d Wk|Wv) @ (64d x 72jc)
__global__ __launch_bounds__(256) void kW(
    const float* __restrict__ Wk, const float* __restrict__ Wv,
    const float* __restrict__ qr, const float* __restrict__ Wor,
    unsigned short* __restrict__ Wth, unsigned short* __restrict__ Wtl)
{
    __shared__ float As[16 * 68];
    __shared__ float Bt[72 * 68];   // [jc][d]
    const int b = blockIdx.x, t = threadIdx.x;
    const int g = b & 3, i0 = (b >> 2) * 16;
    #pragma unroll
    for (int jj = 0; jj < 16; ++jj) {
        const int i2 = t + 256 * jj;    // < 4096
        const int d = i2 & 63, col = i2 >> 6;
        Bt[col * 68 + d] = qr[(col >> 2) * 1024 + (g * 4 + (col & 3)) * 64 + d];
    }
    #pragma unroll
    for (int jj = 0; jj < 2; ++jj) {
        const int i2 = t + 256 * jj;    // < 512
        const int d = i2 & 63, vc = i2 >> 6;
        Bt[(64 + vc) * 68 + d] = Wor[((g * 4 + (vc >> 1)) * 64 + d) * 2 + (vc & 1)];
    }
    {
        const int i = t >> 4, dc = (t & 15) * 4;
        *(float4*)&As[i * 68 + dc] = *(const float4*)(Wk + (size_t)(i0 + i) * 256 + g * 64 + dc);
    }
    __syncthreads();
    const int jc = t & 63, iq = t >> 6;
    {
        float o4[4] = {0.f, 0.f, 0.f, 0.f};
        #pragma unroll
        for (int dc = 0; dc < 16; ++dc) {
            const float4 bv = *(const float4*)&Bt[jc * 68 + dc * 4];
            #pragma unroll
            for (int r = 0; r < 4; ++r) {
                const float4 av = *(const float4*)&As[(iq * 4 + r) * 68 + dc * 4];
                o4[r] = fmaf(av.x, bv.x, o4[r]);
                o4[r] = fmaf(av.y, bv.y, o4[r]);
                o4[r] = fmaf(av.z, bv.z, o4[r]);
                o4[r] = fmaf(av.w, bv.w, o4[r]);
            }
        }
        const int j = (jc >> 2) * 16 + g * 4 + (jc & 3);
        #pragma unroll
        for (int r = 0; r < 4; ++r) {
            unsigned short hh, ll;
            split_bf16(o4[r] * 0.125f, hh, ll);   // 1/sqrt(HD) folded in
            const size_t o = pidx(j, i0 + iq * 4 + r);
            Wth[o] = hh;
            Wtl[o] = ll;
        }
    }
    __syncthreads();
    {
        const int i = t >> 4, dc = (t & 15) * 4;
        *(float4*)&As[i * 68 + dc] = *(const float4*)(Wv + (size_t)(i0 + i) * 256 + g * 64 + dc);
    }
    __syncthreads();
    if (t < 128) {
        const int il = t >> 3, vc = t & 7;
        float acc = 0.f;
        #pragma unroll
        for (int dc = 0; dc < 16; ++dc) {
            const float4 av = *(const float4*)&As[il * 68 + dc * 4];
            const float4 bv = *(const float4*)&Bt[(64 + vc) * 68 + dc * 4];
            acc = fmaf(av.x, bv.x, acc);
            acc = fmaf(av.y, bv.y, acc);
            acc = fmaf(av.z, bv.z, acc);
            acc = fmaf(av.w, bv.w, acc);
        }
        const int j = 256 + (g * 4 + (vc >> 1)) * 2 + (vc & 1);
        unsigned short hh, ll;
        split_bf16(acc, hh, ll);
        const size_t o = pidx(j, i0 + il);
        Wth[o] = hh;
        Wtl[o] = ll;
    }
}

// ------- k2: MFMA GEMM, tile 64x48, 4 waves = 4 K-quarters, contiguous 1KB loads ------
__global__ __launch_bounds__(256, 2) void k2(
    const unsigned short* __restrict__ Ahg, const unsigned short* __restrict__ Alg,
    const unsigned short* __restrict__ Wth, const unsigned short* __restrict__ Wtl,
    float* __restrict__ S0, float* __restrict__ VW0)
{
    __shared__ float red[4][64][52];            // 52 KB
    const int m0 = blockIdx.x * 64;
    const int by = blockIdx.y;                  // n0 = by*48
    const int t = threadIdx.x;
    const int w = t >> 6, lane = t & 63;
    const int l16 = lane & 15, quad = lane >> 4;

    // packed bases: region (rb, kb) at rb*16384 + kb*512; wave w owns kb = w*8 + it
    const size_t abase = (size_t)blockIdx.x * 4 * 16384 + (size_t)w * 8 * 512 + lane * 8;
    const size_t bbase = (size_t)by * 3 * 16384 + (size_t)w * 8 * 512 + lane * 8;
    const unsigned short* pah = Ahg + abase;
    const unsigned short* pal = Alg + abase;
    const unsigned short* pbh = Wth + bbase;
    const unsigned short* pbl = Wtl + bbase;

    v4f acc[4][3];
    #pragma unroll
    for (int i = 0; i < 4; ++i)
        #pragma unroll
        for (int j = 0; j < 3; ++j) acc[i][j] = (v4f)(0.f);

    v8s fah[2][4], fal[2][4], fbh[2][3], fbl[2][3];
    #pragma unroll
    for (int s = 0; s < 4; ++s) {               // prologue: it=0 fragments (1KB each)
        fah[0][s] = *(const v8s*)(pah + s * 16384);
        fal[0][s] = *(const v8s*)(pal + s * 16384);
    }
    #pragma unroll
    for (int s = 0; s < 3; ++s) {
        fbh[0][s] = *(const v8s*)(pbh + s * 16384);
        fbl[0][s] = *(const v8s*)(pbl + s * 16384);
    }
    #pragma unroll 8
    for (int it = 0; it < 8; ++it) {            // 8 x BK=32 covers this wave's 256 k
        const int cur = it & 1, nxt = cur ^ 1;
        if (it < 7) {                           // issue next-iter loads under MFMAs
            const int ko = (it + 1) * 512;
            #pragma unroll
            for (int s = 0; s < 4; ++s) {
                fah[nxt][s] = *(const v8s*)(pah + s * 16384 + ko);
                fal[nxt][s] = *(const v8s*)(pal + s * 16384 + ko);
            }
            #pragma unroll
            for (int s = 0; s < 3; ++s) {
                fbh[nxt][s] = *(const v8s*)(pbh + s * 16384 + ko);
                fbl[nxt][s] = *(const v8s*)(pbl + s * 16384 + ko);
            }
        }
        __builtin_amdgcn_s_setprio(1);          // keep MFMA pipe fed (waves are
        #pragma unroll                          // barrier-free, role-diverse)
        for (int ms = 0; ms < 4; ++ms)
            #pragma unroll
            for (int ns = 0; ns < 3; ++ns) {
                acc[ms][ns] = __builtin_amdgcn_mfma_f32_16x16x32_bf16(fal[cur][ms], fbh[cur][ns], acc[ms][ns], 0, 0, 0);
                acc[ms][ns] = __builtin_amdgcn_mfma_f32_16x16x32_bf16(fah[cur][ms], fbl[cur][ns], acc[ms][ns], 0, 0, 0);
                acc[ms][ns] = __builtin_amdgcn_mfma_f32_16x16x32_bf16(fah[cur][ms], fbh[cur][ns], acc[ms][ns], 0, 0, 0);
            }
        __builtin_amdgcn_s_setprio(0);
    }

    // cross-wave K reduction in LDS, then final S/VW store (no partials)
    #pragma unroll
    for (int ms = 0; ms < 4; ++ms)
        #pragma unroll
        for (int ns = 0; ns < 3; ++ns)
            *(v4f*)&red[w][lane][(ms * 3 + ns) * 4] = acc[ms][ns];
    __syncthreads();
    // thread (w, lane) outputs the ms = w row-block, all ns
    #pragma unroll
    for (int ns = 0; ns < 3; ++ns) {
        const int j = by * 48 + ns * 16 + l16;  // < 288 always
        const int fo = (w * 3 + ns) * 4;
        const v4f s0 = *(const v4f*)&red[0][lane][fo];
        const v4f s1 = *(const v4f*)&red[1][lane][fo];
        const v4f s2 = *(const v4f*)&red[2][lane][fo];
        const v4f s3 = *(const v4f*)&red[3][lane][fo];
        const v4f sv = s0 + s1 + s2 + s3;
        const int m = m0 + w * 16 + quad * 4;   // C/D: col=lane&15, row=quad*4+reg
        const int bb = m >> 9, tt = m & 511;
        float* dst = (j < 256)                  // wave-uniform per (by, ns)
            ? S0  + (size_t)((bb * 16 + (j >> 4)) * 16 + (j & 15)) * SROW + 32 + tt
            : VW0 + (size_t)(bb * 32 + (j - 256)) * SROW + 32 + tt;
        *(float4*)dst = make_float4(sv[0], sv[1], sv[2], sv[3]);
    }
}

// ---------------- k3: exp + sliding-window softmax + head-reduce (quarter-m) -------
__global__ __launch_bounds__(256) void k3(
    const float* __restrict__ S, const float* __restrict__ VW,
    const float* __restrict__ brp, float* __restrict__ out)
{
    __shared__ float Es[16 * 164];
    __shared__ float EVs[32 * 164];
    const int b = blockIdx.x, q = blockIdx.y, qt = blockIdx.z;
    const int tbase = qt * 128;
    const int t = threadIdx.x;
    for (int idx = t; idx < 640; idx += 256) {          // 16 h x 40 float4 (wi<160)
        const int h = idx / 40, g = idx - h * 40;
        const size_t off = (size_t)((b * 16 + q) * 16 + h) * SROW + tbase + g * 4;
        const float4 a = *(const float4*)(S + off);
        float4 e;
        e.x = __expf(a.x); e.y = __expf(a.y);
        e.z = __expf(a.z); e.w = __expf(a.w);
        *(float4*)(Es + h * 164 + g * 4) = e;
    }
    __syncthreads();
    for (int idx = t; idx < 1280; idx += 256) {         // 32 hc x 40 float4
        const int hc = idx / 40, g = idx - hc * 40;
        const size_t off = (size_t)(b * 32 + hc) * SROW + tbase + g * 4;
        const float4 v0 = *(const float4*)(VW + off);
        const float4 e = *(const float4*)(Es + (hc >> 1) * 164 + g * 4);
        float4 rr;
        rr.x = e.x * v0.x; rr.y = e.y * v0.y;
        rr.z = e.z * v0.z; rr.w = e.w * v0.w;
        *(float4*)(EVs + hc * 164 + g * 4) = rr;
    }
    __syncthreads();
    const int h = t & 15, mg = t >> 4;
    const float* ep = Es + h * 164 + mg * 8;
    const float* e0 = EVs + (2 * h) * 164 + mg * 8;
    const float* e1 = EVs + (2 * h + 1) * 164 + mg * 8;
    float den = 0.f, n0s = 0.f, n1s = 0.f;
    #pragma unroll
    for (int s = 0; s < 32; ++s) {
        const int ss = 1 + ((s + 2 * h) & 31);          // bank-rotated
        den += ep[ss]; n0s += e0[ss]; n1s += e1[ss];
    }
    const float br0 = brp[0], br1 = brp[1];
    #pragma unroll
    for (int u = 0; u < 8; ++u) {
        const float inv = __builtin_amdgcn_rcpf(den);
        float c0 = n0s * inv, c1 = n1s * inv;
        #pragma unroll
        for (int w = 1; w < 16; w <<= 1) {
            c0 += __shfl_xor(c0, w, 64);
            c1 += __shfl_xor(c1, w, 64);
        }
        if (h == 0) {
            const int m = tbase + mg * 8 + u;
            float* o = out + (size_t)((b * 512 + m) * 16 + q) * 2;
            o[0] = c0 + br0;
            o[1] = c1 + br1;
        }
        if (u < 7) {
            den += ep[33 + u] - ep[1 + u];
            n0s += e0[33 + u] - e0[1 + u];
            n1s += e1[33 + u] - e1[1 + u];
        }
    }
}

extern "C" void kernel_launch(void* const* d_in, const int* in_sizes, int n_in,
                              void* d_out, int out_size, void* d_ws, size_t ws_size,
                              hipStream_t stream)
{
    (void)in_sizes; (void)n_in; (void)out_size; (void)ws_size;
    const float* h  = (const float*)d_in[0];
    const float* fc = (const float*)d_in[1];
    const float* fs = (const float*)d_in[2];
    const float* Wq = (const float*)d_in[3];
    const float* Wk = (const float*)d_in[4];
    const float* Wv = (const float*)d_in[5];
    const float* Wo = (const float*)d_in[6];
    const float* oq = (const float*)d_in[7];
    const float* Wr = (const float*)d_in[8];
    const float* br = (const float*)d_in[9];
    float* ws = (float*)d_ws;
    float* Wor  = ws + OFF_WOR;
    float* qr   = ws + OFF_QR;
    unsigned short* Wth = (unsigned short*)(ws + OFF_WTH);
    unsigned short* Wtl = (unsigned short*)(ws + OFF_WTL);
    float* S0   = ws + OFF_S0;
    float* VW0  = ws + OFF_VW0;
    unsigned short* Ahg = (unsigned short*)(ws + OFF_AH);
    unsigned short* Alg = (unsigned short*)(ws + OFF_AL);
    float* out = (float*)d_out;

    hipLaunchKernelGGL(kP, dim3(1096), dim3(256), 0, stream,
                       oq, Wq, fc, fs, Wo, Wr, h, qr, Wor, S0, VW0, Ahg, Alg);
    hipLaunchKernelGGL(kW, dim3(256), dim3(256), 0, stream, Wk, Wv, qr, Wor, Wth, Wtl);
    hipLaunchKernelGGL(k2, dim3(64, 6), dim3(256), 0, stream, Ahg, Alg, Wth, Wtl, S0, VW0);
    hipLaunchKernelGGL(k3, dim3(8, 16, 4), dim3(256), 0, stream, S0, VW0, br, out);
}

// Round 5
// 113.588 us; speedup vs baseline: 1.2159x; 1.0264x over previous
//
#include <hip/hip_runtime.h>

// B=8, MB=512, IN=1024, EMB=1024, H=16, KVH=4, HD=64, BS=16, K=32
//
// S[b,t,h,q]  = h[b,t] . (Wk_head @ qr[q,h,:]) / 8
// VW[b,t,h,c] = h[b,t] . (Wv_head @ (Wo@Wr)[h*64:(h+1)*64, c])
// vel[b,m,q,c] = br[c] + sum_h [win-sum E*VW] / [win-sum E],  E=exp(S)
// GEMM 4096x1024x288, 2-term split-bf16 MFMA: C = A*Bh + A*Bl
// (A = RNE-bf16(h): dropping the A-lo plane costs ~1e-4 in out vs 3.9e-3
//  threshold; saves 8.4 MB of kP writes and 1/3 of k2's MFMAs.)
//
// Fragment-packed operand layout: A and B stored as [rb16][kb32][quad][l16][8k]
// so a wave's MFMA fragment load is ONE contiguous 1KB global_load_dwordx4.
// k2: setprio(1) around the MFMA cluster (4 barrier-free K-quarter waves).

typedef __attribute__((ext_vector_type(8))) short v8s;
typedef __attribute__((ext_vector_type(4))) float v4f;

// ws layout (floats)
#define OFF_WOR  0u          // [1024][2]
#define OFF_QR   2048u       // [16][1024]
#define OFF_WTH  18432u      // bf16 hi, packed [18 jb][32 kb][4 quad][16 l][8]
#define OFF_WTL  182272u     // bf16 lo
#define OFF_S0   346112u     // [2048 rows][544]  row=((b*16+q)*16+h), data at [32..544)
#define OFF_VW0  2574336u    // [256 rows][544]   row=b*32+(h*2+c)
#define OFF_AH   2852864u    // bf16 RNE of h, packed [256 mb][32 kb][4 quad][16 l][8]
#define SROW 544

__device__ __forceinline__ void split_bf16(float a, unsigned short& h, unsigned short& l) {
    const unsigned u = __float_as_uint(a);
    h = (unsigned short)(u >> 16);
    const float r = a - __uint_as_float(u & 0xFFFF0000u);   // exact residual
    unsigned v = __float_as_uint(r);
    v += 0x7FFFu + ((v >> 16) & 1u);                        // RNE to bf16
    l = (unsigned short)(v >> 16);
}

__device__ __forceinline__ unsigned short bf16_rne(float a) {
    unsigned u = __float_as_uint(a);
    u += 0x7FFFu + ((u >> 16) & 1u);                        // RNE to bf16
    return (unsigned short)(u >> 16);
}

// packed index for element (row j, k i):  jb=j>>4, kb=i>>5, quad=(i>>3)&3, l=j&15, kk=i&7
__device__ __forceinline__ size_t pidx(int j, int i) {
    return (size_t)(j >> 4) * 16384 + (size_t)((i >> 5)) * 512
         + (size_t)(((i >> 3) & 3) * 128 + (j & 15) * 8 + (i & 7));
}

// ---- kP: qr (proj+RoPE) | Wor = Wo@Wr | h -> packed Ah (RNE) | zero pads ----
__global__ __launch_bounds__(256) void kP(
    const float* __restrict__ oq, const float* __restrict__ Wq,
    const float* __restrict__ fc, const float* __restrict__ fs,
    const float* __restrict__ Wo, const float* __restrict__ Wr,
    const float* __restrict__ hsrc,
    float* __restrict__ qr, float* __restrict__ Wor,
    float* __restrict__ S0, float* __restrict__ VW0,
    unsigned short* __restrict__ Ahg)
{
    __shared__ float sm[2048];
    __shared__ unsigned short Hs[16][520];       // 16.6 KB; row stride 1040B
    const int b = blockIdx.x, t = threadIdx.x;
    if (b < 256) {
        // one (q, head) pair: 64 output cols; e-split across 4 waves
        const int q = b >> 4, h = b & 15;
        #pragma unroll
        for (int j = 0; j < 4; ++j) sm[t + 256 * j] = oq[q * 1024 + t + 256 * j];
        __syncthreads();
        const int w = t >> 6, lane = t & 63;
        const float* wq = Wq + (size_t)(w * 256) * 1024 + h * 64 + lane;
        const float* os = sm + w * 256;
        float acc = 0.f;
        #pragma unroll 16
        for (int e = 0; e < 256; ++e) acc = fmaf(os[e], wq[(size_t)e * 1024], acc);
        sm[1024 + w * 64 + lane] = acc;
        __syncthreads();
        if (t < 64) {
            const int d = t, p = d ^ 32;
            const float a1 = sm[1024 + d] + sm[1088 + d] + sm[1152 + d] + sm[1216 + d];
            const float a2 = sm[1024 + p] + sm[1088 + p] + sm[1152 + p] + sm[1216 + p];
            const float c = fc[q * 64 + d], s = fs[q * 64 + d];
            const float rh = (d < 32) ? -a2 : a2;
            qr[q * 1024 + h * 64 + d] = fmaf(a1, c, rh * s);
        }
        return;
    }
    if (b < 512) {
        // Wor = Wo @ Wr  (4 rows/block, wave per row)
        #pragma unroll
        for (int j = 0; j < 8; ++j) sm[t + 256 * j] = Wr[t + 256 * j];
        __syncthreads();
        const int i = (b - 256) * 4 + (t >> 6);
        const int lane = t & 63;
        float a0 = 0.f, a1 = 0.f;
        const float* wo = Wo + (size_t)i * 1024 + lane;
        #pragma unroll
        for (int j = 0; j < 16; ++j) {
            const float w = wo[j * 64];
            const int e = lane + j * 64;
            a0 = fmaf(w, sm[2 * e], a0);
            a1 = fmaf(w, sm[2 * e + 1], a1);
        }
        #pragma unroll
        for (int w = 1; w < 64; w <<= 1) {
            a0 += __shfl_xor(a0, w, 64);
            a1 += __shfl_xor(a1, w, 64);
        }
        if (lane == 0) { Wor[i * 2] = a0; Wor[i * 2 + 1] = a1; }
        return;
    }
    if (b < 1024) {
        // h -> packed RNE bf16: block = 16 rows x 512 k  (mb, kseg)
        const int b2 = b - 512;
        const int mb = b2 >> 1, kseg = b2 & 1;
        const int w = t >> 6, lane = t & 63;
        #pragma unroll
        for (int i = 0; i < 4; ++i) {
            const int r = i * 4 + w;
            const float* src = hsrc + (size_t)(mb * 16 + r) * 1024 + kseg * 512 + lane * 8;
            const float4 x0 = *(const float4*)src;
            const float4 x1 = *(const float4*)(src + 4);
            const float af[8] = {x0.x, x0.y, x0.z, x0.w, x1.x, x1.y, x1.z, x1.w};
            v8s hv;
            #pragma unroll
            for (int j = 0; j < 8; ++j) hv[j] = (short)bf16_rne(af[j]);
            *(v8s*)&Hs[r][lane * 8] = hv;
        }
        __syncthreads();
        // write packed: region = mb*16384 + kseg*8192, slot o = i*2048 + t*8
        unsigned short* dh = Ahg + (size_t)mb * 16384 + kseg * 8192;
        const int l16 = lane & 15, quad = lane >> 4;
        #pragma unroll
        for (int i = 0; i < 4; ++i) {
            const int kc = (i * 4 + w) * 32 + quad * 8;   // local col in [0,512)
            const v8s hv = *(const v8s*)&Hs[l16][kc];
            *(v8s*)(dh + i * 2048 + t * 8) = hv;
        }
        return;
    }
    // zero left-pads (32 floats = 8 float4 per row): S0 (2048 rows) + VW0 (256 rows)
    const int idx = (b - 1024) * 256 + t;  // < 18432
    const float4 z = make_float4(0.f, 0.f, 0.f, 0.f);
    if (idx < 16384)  *(float4*)(S0  + (size_t)(idx >> 3) * SROW + (idx & 7) * 4) = z;
    else              *(float4*)(VW0 + (size_t)((idx - 16384) >> 3) * SROW + (idx & 7) * 4) = z;
}

// ---------------- kW: folded weights -> packed Wth/Wtl bf16 [j][i]-packed ----------------
// per kv-group g, 16-row chunk: (16i x 64d Wk|Wv) @ (64d x 72jc)
__global__ __launch_bounds__(256) void kW(
    const float* __restrict__ Wk, const float* __restrict__ Wv,
    const float* __restrict__ qr, const float* __restrict__ Wor,
    unsigned short* __restrict__ Wth, unsigned short* __restrict__ Wtl)
{
    __shared__ float As[16 * 68];
    __shared__ float Bt[72 * 68];   // [jc][d]
    const int b = blockIdx.x, t = threadIdx.x;
    const int g = b & 3, i0 = (b >> 2) * 16;
    #pragma unroll
    for (int jj = 0; jj < 16; ++jj) {
        const int i2 = t + 256 * jj;    // < 4096
        const int d = i2 & 63, col = i2 >> 6;
        Bt[col * 68 + d] = qr[(col >> 2) * 1024 + (g * 4 + (col & 3)) * 64 + d];
    }
    #pragma unroll
    for (int jj = 0; jj < 2; ++jj) {
        const int i2 = t + 256 * jj;    // < 512
        const int d = i2 & 63, vc = i2 >> 6;
        Bt[(64 + vc) * 68 + d] = Wor[((g * 4 + (vc >> 1)) * 64 + d) * 2 + (vc & 1)];
    }
    {
        const int i = t >> 4, dc = (t & 15) * 4;
        *(float4*)&As[i * 68 + dc] = *(const float4*)(Wk + (size_t)(i0 + i) * 256 + g * 64 + dc);
    }
    __syncthreads();
    const int jc = t & 63, iq = t >> 6;
    {
        float o4[4] = {0.f, 0.f, 0.f, 0.f};
        #pragma unroll
        for (int dc = 0; dc < 16; ++dc) {
            const float4 bv = *(const float4*)&Bt[jc * 68 + dc * 4];
            #pragma unroll
            for (int r = 0; r < 4; ++r) {
                const float4 av = *(const float4*)&As[(iq * 4 + r) * 68 + dc * 4];
                o4[r] = fmaf(av.x, bv.x, o4[r]);
                o4[r] = fmaf(av.y, bv.y, o4[r]);
                o4[r] = fmaf(av.z, bv.z, o4[r]);
                o4[r] = fmaf(av.w, bv.w, o4[r]);
            }
        }
        const int j = (jc >> 2) * 16 + g * 4 + (jc & 3);
        #pragma unroll
        for (int r = 0; r < 4; ++r) {
            unsigned short hh, ll;
            split_bf16(o4[r] * 0.125f, hh, ll);   // 1/sqrt(HD) folded in
            const size_t o = pidx(j, i0 + iq * 4 + r);
            Wth[o] = hh;
            Wtl[o] = ll;
        }
    }
    __syncthreads();
    {
        const int i = t >> 4, dc = (t & 15) * 4;
        *(float4*)&As[i * 68 + dc] = *(const float4*)(Wv + (size_t)(i0 + i) * 256 + g * 64 + dc);
    }
    __syncthreads();
    if (t < 128) {
        const int il = t >> 3, vc = t & 7;
        float acc = 0.f;
        #pragma unroll
        for (int dc = 0; dc < 16; ++dc) {
            const float4 av = *(const float4*)&As[il * 68 + dc * 4];
            const float4 bv = *(const float4*)&Bt[(64 + vc) * 68 + dc * 4];
            acc = fmaf(av.x, bv.x, acc);
            acc = fmaf(av.y, bv.y, acc);
            acc = fmaf(av.z, bv.z, acc);
            acc = fmaf(av.w, bv.w, acc);
        }
        const int j = 256 + (g * 4 + (vc >> 1)) * 2 + (vc & 1);
        unsigned short hh, ll;
        split_bf16(acc, hh, ll);
        const size_t o = pidx(j, i0 + il);
        Wth[o] = hh;
        Wtl[o] = ll;
    }
}

// ------- k2: MFMA GEMM, tile 64x48, 4 waves = 4 K-quarters, contiguous 1KB loads ------
__global__ __launch_bounds__(256, 2) void k2(
    const unsigned short* __restrict__ Ahg,
    const unsigned short* __restrict__ Wth, const unsigned short* __restrict__ Wtl,
    float* __restrict__ S0, float* __restrict__ VW0)
{
    __shared__ float red[4][64][52];            // 52 KB
    const int m0 = blockIdx.x * 64;
    const int by = blockIdx.y;                  // n0 = by*48
    const int t = threadIdx.x;
    const int w = t >> 6, lane = t & 63;
    const int l16 = lane & 15, quad = lane >> 4;

    // packed bases: region (rb, kb) at rb*16384 + kb*512; wave w owns kb = w*8 + it
    const size_t abase = (size_t)blockIdx.x * 4 * 16384 + (size_t)w * 8 * 512 + lane * 8;
    const size_t bbase = (size_t)by * 3 * 16384 + (size_t)w * 8 * 512 + lane * 8;
    const unsigned short* pah = Ahg + abase;
    const unsigned short* pbh = Wth + bbase;
    const unsigned short* pbl = Wtl + bbase;

    v4f acc[4][3];
    #pragma unroll
    for (int i = 0; i < 4; ++i)
        #pragma unroll
        for (int j = 0; j < 3; ++j) acc[i][j] = (v4f)(0.f);

    v8s fah[2][4], fbh[2][3], fbl[2][3];
    #pragma unroll
    for (int s = 0; s < 4; ++s)                 // prologue: it=0 fragments (1KB each)
        fah[0][s] = *(const v8s*)(pah + s * 16384);
    #pragma unroll
    for (int s = 0; s < 3; ++s) {
        fbh[0][s] = *(const v8s*)(pbh + s * 16384);
        fbl[0][s] = *(const v8s*)(pbl + s * 16384);
    }
    #pragma unroll 8
    for (int it = 0; it < 8; ++it) {            // 8 x BK=32 covers this wave's 256 k
        const int cur = it & 1, nxt = cur ^ 1;
        if (it < 7) {                           // issue next-iter loads under MFMAs
            const int ko = (it + 1) * 512;
            #pragma unroll
            for (int s = 0; s < 4; ++s)
                fah[nxt][s] = *(const v8s*)(pah + s * 16384 + ko);
            #pragma unroll
            for (int s = 0; s < 3; ++s) {
                fbh[nxt][s] = *(const v8s*)(pbh + s * 16384 + ko);
                fbl[nxt][s] = *(const v8s*)(pbl + s * 16384 + ko);
            }
        }
        __builtin_amdgcn_s_setprio(1);          // barrier-free role-diverse waves
        #pragma unroll
        for (int ms = 0; ms < 4; ++ms)
            #pragma unroll
            for (int ns = 0; ns < 3; ++ns) {
                acc[ms][ns] = __builtin_amdgcn_mfma_f32_16x16x32_bf16(fah[cur][ms], fbl[cur][ns], acc[ms][ns], 0, 0, 0);
                acc[ms][ns] = __builtin_amdgcn_mfma_f32_16x16x32_bf16(fah[cur][ms], fbh[cur][ns], acc[ms][ns], 0, 0, 0);
            }
        __builtin_amdgcn_s_setprio(0);
    }

    // cross-wave K reduction in LDS, then final S/VW store (no partials)
    #pragma unroll
    for (int ms = 0; ms < 4; ++ms)
        #pragma unroll
        for (int ns = 0; ns < 3; ++ns)
            *(v4f*)&red[w][lane][(ms * 3 + ns) * 4] = acc[ms][ns];
    __syncthreads();
    // thread (w, lane) outputs the ms = w row-block, all ns
    #pragma unroll
    for (int ns = 0; ns < 3; ++ns) {
        const int j = by * 48 + ns * 16 + l16;  // < 288 always
        const int fo = (w * 3 + ns) * 4;
        const v4f s0 = *(const v4f*)&red[0][lane][fo];
        const v4f s1 = *(const v4f*)&red[1][lane][fo];
        const v4f s2 = *(const v4f*)&red[2][lane][fo];
        const v4f s3 = *(const v4f*)&red[3][lane][fo];
        const v4f sv = s0 + s1 + s2 + s3;
        const int m = m0 + w * 16 + quad * 4;   // C/D: col=lane&15, row=quad*4+reg
        const int bb = m >> 9, tt = m & 511;
        float* dst = (j < 256)                  // wave-uniform per (by, ns)
            ? S0  + (size_t)((bb * 16 + (j >> 4)) * 16 + (j & 15)) * SROW + 32 + tt
            : VW0 + (size_t)(bb * 32 + (j - 256)) * SROW + 32 + tt;
        *(float4*)dst = make_float4(sv[0], sv[1], sv[2], sv[3]);
    }
}

// ---------------- k3: exp + sliding-window softmax + head-reduce (quarter-m) -------
__global__ __launch_bounds__(256) void k3(
    const float* __restrict__ S, const float* __restrict__ VW,
    const float* __restrict__ brp, float* __restrict__ out)
{
    __shared__ float Es[16 * 164];
    __shared__ float EVs[32 * 164];
    const int b = blockIdx.x, q = blockIdx.y, qt = blockIdx.z;
    const int tbase = qt * 128;
    const int t = threadIdx.x;
    for (int idx = t; idx < 640; idx += 256) {          // 16 h x 40 float4 (wi<160)
        const int h = idx / 40, g = idx - h * 40;
        const size_t off = (size_t)((b * 16 + q) * 16 + h) * SROW + tbase + g * 4;
        const float4 a = *(const float4*)(S + off);
        float4 e;
        e.x = __expf(a.x); e.y = __expf(a.y);
        e.z = __expf(a.z); e.w = __expf(a.w);
        *(float4*)(Es + h * 164 + g * 4) = e;
    }
    __syncthreads();
    for (int idx = t; idx < 1280; idx += 256) {         // 32 hc x 40 float4
        const int hc = idx / 40, g = idx - hc * 40;
        const size_t off = (size_t)(b * 32 + hc) * SROW + tbase + g * 4;
        const float4 v0 = *(const float4*)(VW + off);
        const float4 e = *(const float4*)(Es + (hc >> 1) * 164 + g * 4);
        float4 rr;
        rr.x = e.x * v0.x; rr.y = e.y * v0.y;
        rr.z = e.z * v0.z; rr.w = e.w * v0.w;
        *(float4*)(EVs + hc * 164 + g * 4) = rr;
    }
    __syncthreads();
    const int h = t & 15, mg = t >> 4;
    const float* ep = Es + h * 164 + mg * 8;
    const float* e0 = EVs + (2 * h) * 164 + mg * 8;
    const float* e1 = EVs + (2 * h + 1) * 164 + mg * 8;
    float den = 0.f, n0s = 0.f, n1s = 0.f;
    #pragma unroll
    for (int s = 0; s < 32; ++s) {
        const int ss = 1 + ((s + 2 * h) & 31);          // bank-rotated
        den += ep[ss]; n0s += e0[ss]; n1s += e1[ss];
    }
    const float br0 = brp[0], br1 = brp[1];
    #pragma unroll
    for (int u = 0; u < 8; ++u) {
        const float inv = __builtin_amdgcn_rcpf(den);
        float c0 = n0s * inv, c1 = n1s * inv;
        #pragma unroll
        for (int w = 1; w < 16; w <<= 1) {
            c0 += __shfl_xor(c0, w, 64);
            c1 += __shfl_xor(c1, w, 64);
        }
        if (h == 0) {
            const int m = tbase + mg * 8 + u;
            float* o = out + (size_t)((b * 512 + m) * 16 + q) * 2;
            o[0] = c0 + br0;
            o[1] = c1 + br1;
        }
        if (u < 7) {
            den += ep[33 + u] - ep[1 + u];
            n0s += e0[33 + u] - e0[1 + u];
            n1s += e1[33 + u] - e1[1 + u];
        }
    }
}

extern "C" void kernel_launch(void* const* d_in, const int* in_sizes, int n_in,
                              void* d_out, int out_size, void* d_ws, size_t ws_size,
                              hipStream_t stream)
{
    (void)in_sizes; (void)n_in; (void)out_size; (void)ws_size;
    const float* h  = (const float*)d_in[0];
    const float* fc = (const float*)d_in[1];
    const float* fs = (const float*)d_in[2];
    const float* Wq = (const float*)d_in[3];
    const float* Wk = (const float*)d_in[4];
    const float* Wv = (const float*)d_in[5];
    const float* Wo = (const float*)d_in[6];
    const float* oq = (const float*)d_in[7];
    const float* Wr = (const float*)d_in[8];
    const float* br = (const float*)d_in[9];
    float* ws = (float*)d_ws;
    float* Wor  = ws + OFF_WOR;
    float* qr   = ws + OFF_QR;
    unsigned short* Wth = (unsigned short*)(ws + OFF_WTH);
    unsigned short* Wtl = (unsigned short*)(ws + OFF_WTL);
    float* S0   = ws + OFF_S0;
    float* VW0  = ws + OFF_VW0;
    unsigned short* Ahg = (unsigned short*)(ws + OFF_AH);
    float* out = (float*)d_out;

    hipLaunchKernelGGL(kP, dim3(1096), dim3(256), 0, stream,
                       oq, Wq, fc, fs, Wo, Wr, h, qr, Wor, S0, VW0, Ahg);
    hipLaunchKernelGGL(kW, dim3(256), dim3(256), 0, stream, Wk, Wv, qr, Wor, Wth, Wtl);
    hipLaunchKernelGGL(k2, dim3(64, 6), dim3(256), 0, stream, Ahg, Wth, Wtl, S0, VW0);
    hipLaunchKernelGGL(k3, dim3(8, 16, 4), dim3(256), 0, stream, S0, VW0, br, out);
}